// Round 3
// baseline (387.122 us; speedup 1.0000x reference)
//
#include <hip/hip_runtime.h>

typedef unsigned int u32;

#define LOG2E 1.4426950408889634f
#define LN2   0.6931471805599453f

// lane-dependent-indexed weights staged in LDS (floats offsets)
#define IPW  0      // in_proj  (32x8)  256
#define CW   256    // conv_w   (16x4)  64
#define XPW  320    // x_proj   (33x16) 528
#define DTW  848    // 16
#define DTB  864    // 16
#define DSK  880    // 16
#define CB   896    // 16
#define OW   912    // out_w (8x16) 128
#define WTOT 1040

__device__ __forceinline__ float fexp2(float x){ return __builtin_amdgcn_exp2f(x); }
__device__ __forceinline__ float flog2(float x){ return __builtin_amdgcn_logf(x); }
__device__ __forceinline__ float frcp (float x){ return __builtin_amdgcn_rcpf(x); }
__device__ __forceinline__ float siluf(float x){ return x * frcp(1.0f + fexp2(-x * LOG2E)); }
__device__ __forceinline__ float softplusf(float x){
  float r = flog2(1.0f + fexp2(x * LOG2E)) * LN2;
  return x > 15.0f ? x : r;
}

// one wave (64 threads) per (channel c, sequence n); Lf=256 in 8 chunks of 32.
// phases: lane=(t2,hb) 2 lanes/timestep; scan: lane=(di,sg) 4 states/lane.
__global__ __launch_bounds__(64, 3) void mamba_k(
    const float* __restrict__ xg,   const float* __restrict__ lwg,  const float* __restrict__ lbg,
    const float* __restrict__ ipwg, const float* __restrict__ cwg,  const float* __restrict__ cbg,
    const float* __restrict__ xpwg, const float* __restrict__ dtwg, const float* __restrict__ dtbg,
    const float* __restrict__ alogg,const float* __restrict__ dskg, const float* __restrict__ owg,
    const float* __restrict__ bwg,  const float* __restrict__ bbg,  float* __restrict__ feat)
{
  __shared__ __align__(16) float s_w [WTOT];   // 4160 B
  __shared__ __align__(16) float s_BC[32*36];  // [t]: B[0..15], C[16..31], pad; 16B-aligned rows
  __shared__ __align__(16) float s_dx[32*34];  // [t][di]: (dt,xc) float2, 8B-aligned
  __shared__ __align__(16) float s_xy[35*17];  // conv staging rows 0..34; y overlays rows 0..31

  const int lane = threadIdx.x;
  const int c    = blockIdx.x & 7;       // consecutive bids share n -> x line reuse
  const int n    = blockIdx.x >> 3;
  const int t2   = lane >> 1;            // phase timestep within chunk
  const int hb   = lane & 1;             // phase half (owns di = hb*8..hb*8+7)
  const int di   = lane >> 2;            // scan channel
  const int sg   = lane & 3;             // scan state-quad

  // ---- stage lane-dep weights into LDS ----
  #pragma unroll
  for (int i = lane; i < 256; i += 64) s_w[IPW+i] = ipwg[c*256+i];
  s_w[CW+lane] = cwg[c*64+lane];
  for (int i = lane; i < 528; i += 64) s_w[XPW+i] = xpwg[c*528+i];
  #pragma unroll
  for (int i = lane; i < 128; i += 64) s_w[OW+i]  = owg[c*128+i];
  if (lane < 16) {
    s_w[DTW+lane] = dtwg[c*16+lane];
    s_w[DTB+lane] = dtbg[c*16+lane];
    s_w[DSK+lane] = dskg[c*16+lane];
    s_w[CB +lane] = cbg [c*16+lane];
  }
  if (lane < 48) s_xy[(lane>>4)*17 + (lane&15)] = 0.f;   // conv zero history

  // per-lane A (pre-scaled: dA = exp2(dt*Am))
  float Am[4];
  {
    const int ab = c*256 + di*16 + sg*4;
    #pragma unroll
    for (int k = 0; k < 4; ++k) Am[k] = -fexp2(alogg[ab+k] * LOG2E) * LOG2E;
  }

  // prefetch all 8 x values (stride-4KB scattered reads, issued up-front)
  float xv[8];
  {
    const int xbase = (n>>7)*262144 + (n&127)*8 + c;
    #pragma unroll
    for (int ch = 0; ch < 8; ++ch) xv[ch] = xg[xbase + (ch*32 + t2)*1024];
  }
  __syncthreads();

  float h0=0.f, h1=0.f, h2=0.f, h3=0.f;   // scan state, persists across chunks
  float pacc[8];
  #pragma unroll
  for (int d = 0; d < 8; ++d) pacc[d] = 0.f;

  float xc[8], zg[8];                     // per-lane half-channels, live across scan

  #pragma unroll 1
  for (int ch = 0; ch < 8; ++ch) {
    if (ch > 0) {
      __syncthreads();                    // post done reading y rows
      if (lane < 48) s_xy[(lane>>4)*17 + (lane&15)] = s_xy[((lane>>4)+32)*17 + (lane&15)];
      __syncthreads();                    // copy done before A1 overwrites tail rows
    }
    // ---- A1: lift + in_proj (split: lane writes its half's 8 x_in cols; zg in regs) ----
    {
      const float xval = xv[ch];
      float z[8];
      #pragma unroll
      for (int d = 0; d < 8; ++d) z[d] = xval * lwg[c*8+d] + lbg[c*8+d];  // uniform -> s_load
      float* xrow = s_xy + (t2+3)*17 + hb*8;
      #pragma unroll
      for (int j = 0; j < 8; ++j) {
        const float* wr = s_w + IPW + (hb*8+j)*8;
        float4 w0 = *(const float4*)(wr);
        float4 w1 = *(const float4*)(wr+4);
        xrow[j] = z[0]*w0.x + z[1]*w0.y + z[2]*w0.z + z[3]*w0.w
                + z[4]*w1.x + z[5]*w1.y + z[6]*w1.z + z[7]*w1.w;
      }
      #pragma unroll
      for (int j = 0; j < 8; ++j) {
        const float* wr = s_w + IPW + 128 + (hb*8+j)*8;
        float4 w0 = *(const float4*)(wr);
        float4 w1 = *(const float4*)(wr+4);
        zg[j] = z[0]*w0.x + z[1]*w0.y + z[2]*w0.z + z[3]*w0.w
              + z[4]*w1.x + z[5]*w1.y + z[6]*w1.z + z[7]*w1.w;
      }
    }
    __syncthreads();
    // ---- A2: conv + SiLU + x_proj + dt ----
    {
      #pragma unroll
      for (int j = 0; j < 8; ++j) xc[j] = s_w[CB + hb*8 + j];
      #pragma unroll
      for (int k = 0; k < 4; ++k) {
        const float* row = s_xy + (t2+k)*17 + hb*8;
        #pragma unroll
        for (int j = 0; j < 8; ++j) xc[j] += row[j] * s_w[CW + (hb*8+j)*4 + k];
      }
      #pragma unroll
      for (int j = 0; j < 8; ++j) xc[j] = siluf(xc[j]);
      // full 16-wide xc via partner exchange (DPP quad_perm)
      float xcf[16];
      #pragma unroll
      for (int j = 0; j < 8; ++j) {
        float p = __shfl_xor(xc[j], 1);
        xcf[j]   = hb ? p : xc[j];
        xcf[8+j] = hb ? xc[j] : p;
      }
      // x_proj: hb=0 -> rows 0..16 (dtlo + B), hb=1 -> rows 16..32 (C; j=0 dup/discard)
      float res[17];
      #pragma unroll
      for (int j = 0; j < 17; ++j) {
        const float* wr = s_w + XPW + (hb*16 + j)*16;
        float acc = 0.f;
        #pragma unroll
        for (int q = 0; q < 4; ++q) {
          float4 w = *(const float4*)(wr + q*4);
          acc += xcf[q*4+0]*w.x + xcf[q*4+1]*w.y + xcf[q*4+2]*w.z + xcf[q*4+3]*w.w;
        }
        res[j] = acc;
      }
      float other = __shfl_xor(res[0], 1);
      float dtlo  = hb ? other : res[0];
      // write B (hb=0) / C (hb=1): 4 aligned float4 stores
      float* bc = s_BC + t2*36 + hb*16;
      #pragma unroll
      for (int q = 0; q < 4; ++q)
        *(float4*)(bc + q*4) = make_float4(res[1+q*4], res[2+q*4], res[3+q*4], res[4+q*4]);
      // dt (softplus) + xc into interleaved float2 buffer
      float* dxp = s_dx + t2*34;
      #pragma unroll
      for (int j = 0; j < 8; ++j) {
        const int i = hb*8 + j;
        dxp[i*2]   = softplusf(dtlo * s_w[DTW+i] + s_w[DTB+i]);
        dxp[i*2+1] = xc[j];
      }
    }
    __syncthreads();
    // ---- scan: 32 sequential steps, 4 f32 states/lane ----
    {
      const float* pB = s_BC + sg*4;
      const float* pC = s_BC + 16 + sg*4;
      const float* pd = s_dx + di*2;
      float* py = s_xy + di;
      #pragma unroll 4
      for (int tl = 0; tl < 32; ++tl) {
        float4 bv = *(const float4*)(pB + tl*36);   // broadcast, conflict-free
        float4 cv = *(const float4*)(pC + tl*36);
        float2 dx = *(const float2*)(pd + tl*34);
        float w  = dx.x * dx.y;
        float e0 = fexp2(dx.x*Am[0]);
        float e1 = fexp2(dx.x*Am[1]);
        float e2 = fexp2(dx.x*Am[2]);
        float e3 = fexp2(dx.x*Am[3]);
        h0 = h0*e0 + w*bv.x;
        h1 = h1*e1 + w*bv.y;
        h2 = h2*e2 + w*bv.z;
        h3 = h3*e3 + w*bv.w;
        float yp = h0*cv.x + h1*cv.y + h2*cv.z + h3*cv.w;
        yp += __shfl_xor(yp, 1);
        yp += __shfl_xor(yp, 2);
        if (sg == 0) py[tl*17] = yp;     // y overlays dead conv rows 0..31
      }
    }
    __syncthreads();
    // ---- post: gate + out/blk proj + pooled accumulate ----
    {
      const float* yrow = s_xy + t2*17 + hb*8;
      float yf[8];
      #pragma unroll
      for (int j = 0; j < 8; ++j) {
        const int i = hb*8 + j;
        float g = siluf(zg[j]);
        yf[j] = (yrow[j] + s_w[DSK+i]*xc[j]) * g;
      }
      float outv[8];
      #pragma unroll
      for (int d = 0; d < 8; ++d) {
        const float* wr = s_w + OW + d*16 + hb*8;
        float4 w0 = *(const float4*)(wr);
        float4 w1 = *(const float4*)(wr+4);
        float acc = yf[0]*w0.x + yf[1]*w0.y + yf[2]*w0.z + yf[3]*w0.w
                  + yf[4]*w1.x + yf[5]*w1.y + yf[6]*w1.z + yf[7]*w1.w;
        acc += __shfl_xor(acc, 1);       // combine halves -> full dot in both lanes
        outv[d] = acc;
      }
      #pragma unroll
      for (int d = 0; d < 8; ++d) {
        float acc = bbg[c*8+d];          // uniform -> s_load
        #pragma unroll
        for (int d2 = 0; d2 < 8; ++d2) acc += outv[d2] * bwg[c*64 + d*8 + d2];
        pacc[d] += siluf(acc);           // both halves duplicate -> scale 1/512 at end
      }
    }
  }

  // ---- reduce pooled over 64 lanes (each t counted twice), write feat ----
  #pragma unroll
  for (int d = 0; d < 8; ++d) {
    float v = pacc[d];
    v += __shfl_xor(v, 1);
    v += __shfl_xor(v, 2);
    v += __shfl_xor(v, 4);
    v += __shfl_xor(v, 8);
    v += __shfl_xor(v, 16);
    v += __shfl_xor(v, 32);
    pacc[d] = v;
  }
  if (lane == 0) {
    #pragma unroll
    for (int d = 0; d < 8; ++d) feat[n*64 + c*8 + d] = pacc[d] * (1.0f/512.0f);
  }
}

// LayerNorm over the 64-wide feature dim; one wave per row
__global__ __launch_bounds__(64) void ln_k(const float* __restrict__ feat,
    const float* __restrict__ g, const float* __restrict__ b, float* __restrict__ out)
{
  const int row = blockIdx.x;
  const int l = threadIdx.x;
  float v = feat[row*64 + l];
  float s = v, q = v*v;
  #pragma unroll
  for (int m = 1; m < 64; m <<= 1) { s += __shfl_xor(s, m); q += __shfl_xor(q, m); }
  float mu  = s * (1.0f/64.0f);
  float var = q * (1.0f/64.0f) - mu*mu;
  float rs  = __builtin_amdgcn_rsqf(var + 1e-5f);
  out[row*64 + l] = (v - mu) * rs * g[l] + b[l];
}

extern "C" void kernel_launch(void* const* d_in, const int* in_sizes, int n_in,
                              void* d_out, int out_size, void* d_ws, size_t ws_size,
                              hipStream_t stream)
{
  const float* xg    = (const float*)d_in[0];
  const float* lwg   = (const float*)d_in[1];
  const float* lbg   = (const float*)d_in[2];
  const float* ipwg  = (const float*)d_in[3];
  const float* cwg   = (const float*)d_in[4];
  const float* cbg   = (const float*)d_in[5];
  const float* xpwg  = (const float*)d_in[6];
  const float* dtwg  = (const float*)d_in[7];
  const float* dtbg  = (const float*)d_in[8];
  const float* alogg = (const float*)d_in[9];
  const float* dskg  = (const float*)d_in[10];
  const float* owg   = (const float*)d_in[11];
  const float* bwg   = (const float*)d_in[12];
  const float* bbg   = (const float*)d_in[13];
  const float* lng   = (const float*)d_in[14];
  const float* lnb   = (const float*)d_in[15];
  float* feat = (float*)d_ws;   // 512*64 f32 = 128 KB scratch

  mamba_k<<<dim3(4096), dim3(64), 0, stream>>>(xg, lwg, lbg, ipwg, cwg, cbg, xpwg,
                                               dtwg, dtbg, alogg, dskg, owg, bwg, bbg, feat);
  ln_k<<<dim3(512), dim3(64), 0, stream>>>(feat, lng, lnb, (float*)d_out);
}

// Round 4
// 261.047 us; speedup vs baseline: 1.4830x; 1.4830x over previous
//
#include <hip/hip_runtime.h>

typedef unsigned int u32;

#define LOG2E 1.4426950408889634f
#define LN2   0.6931471805599453f

// lane-dependent-indexed weights staged in LDS (float offsets)
#define IPW  0      // in_proj  (32x8)  256
#define CW   256    // conv_w   (16x4)  64
#define XPW  320    // x_proj   (33x16) 528
#define DTW  848    // 16
#define DTB  864    // 16
#define DSK  880    // 16
#define CB   896    // 16
#define OW   912    // out_w (8x16) 128
#define WTOT 1040

__device__ __forceinline__ float fexp2(float x){ return __builtin_amdgcn_exp2f(x); }
__device__ __forceinline__ float flog2(float x){ return __builtin_amdgcn_logf(x); }
__device__ __forceinline__ float frcp (float x){ return __builtin_amdgcn_rcpf(x); }
__device__ __forceinline__ float siluf(float x){ return x * frcp(1.0f + fexp2(-x * LOG2E)); }
__device__ __forceinline__ float softplusf(float x){
  float r = flog2(1.0f + fexp2(x * LOG2E)) * LN2;
  return x > 15.0f ? x : r;
}

// 16-wide dot of LDS row `wr` with register vector xcf (unrolled, no arrays)
__device__ __forceinline__ float dot16(const float* wr, const float xcf[16]){
  float4 w0 = *(const float4*)(wr);
  float4 w1 = *(const float4*)(wr+4);
  float4 w2 = *(const float4*)(wr+8);
  float4 w3 = *(const float4*)(wr+12);
  return xcf[0]*w0.x + xcf[1]*w0.y + xcf[2]*w0.z + xcf[3]*w0.w
       + xcf[4]*w1.x + xcf[5]*w1.y + xcf[6]*w1.z + xcf[7]*w1.w
       + xcf[8]*w2.x + xcf[9]*w2.y + xcf[10]*w2.z + xcf[11]*w2.w
       + xcf[12]*w3.x+ xcf[13]*w3.y+ xcf[14]*w3.z + xcf[15]*w3.w;
}

// one wave (64 threads) per (channel c, sequence n); Lf=256 in 8 chunks of 32.
// phases: lane=(t2,hb) 2 lanes/timestep; scan: lane=(di,sg) 4 states/lane.
__global__ __launch_bounds__(64) void mamba_k(
    const float* __restrict__ xg,   const float* __restrict__ lwg,  const float* __restrict__ lbg,
    const float* __restrict__ ipwg, const float* __restrict__ cwg,  const float* __restrict__ cbg,
    const float* __restrict__ xpwg, const float* __restrict__ dtwg, const float* __restrict__ dtbg,
    const float* __restrict__ alogg,const float* __restrict__ dskg, const float* __restrict__ owg,
    const float* __restrict__ bwg,  const float* __restrict__ bbg,  float* __restrict__ feat)
{
  __shared__ __align__(16) float s_w [WTOT];   // 4160 B
  __shared__ __align__(16) float s_BC[32*36];  // [t]: B[0..15] | C[16..31] | pad4; 16B-aligned rows
  __shared__ __align__(16) float s_dt[32*17];  // stride 17 (odd): conflict-free
  __shared__ __align__(16) float s_xc[32*17];
  __shared__ __align__(16) float s_xy[35*17];  // conv staging rows 0..34; y overlays rows 0..31

  const int lane = threadIdx.x;
  const int c    = blockIdx.x & 7;       // consecutive bids share n -> x line reuse
  const int n    = blockIdx.x >> 3;
  const int t2   = lane >> 1;            // phase timestep within chunk
  const int hb   = lane & 1;             // phase half (owns di = hb*8..hb*8+7)
  const int di   = lane >> 2;            // scan channel
  const int sg   = lane & 3;             // scan state-quad

  // ---- stage lane-dep weights into LDS ----
  #pragma unroll
  for (int i = lane; i < 256; i += 64) s_w[IPW+i] = ipwg[c*256+i];
  s_w[CW+lane] = cwg[c*64+lane];
  #pragma unroll
  for (int i = lane; i < 528; i += 64) s_w[XPW+i] = xpwg[c*528+i];
  #pragma unroll
  for (int i = lane; i < 128; i += 64) s_w[OW+i]  = owg[c*128+i];
  if (lane < 16) {
    s_w[DTW+lane] = dtwg[c*16+lane];
    s_w[DTB+lane] = dtbg[c*16+lane];
    s_w[DSK+lane] = dskg[c*16+lane];
    s_w[CB +lane] = cbg [c*16+lane];
  }
  if (lane < 48) s_xy[(lane>>4)*17 + (lane&15)] = 0.f;   // conv zero history

  // per-lane A (pre-scaled: dA = exp2(dt*Am))
  float Am0, Am1, Am2, Am3;
  {
    const int ab = c*256 + di*16 + sg*4;
    Am0 = -fexp2(alogg[ab+0] * LOG2E) * LOG2E;
    Am1 = -fexp2(alogg[ab+1] * LOG2E) * LOG2E;
    Am2 = -fexp2(alogg[ab+2] * LOG2E) * LOG2E;
    Am3 = -fexp2(alogg[ab+3] * LOG2E) * LOG2E;
  }
  __syncthreads();

  float h0=0.f, h1=0.f, h2=0.f, h3=0.f;   // scan state, persists across chunks
  float pacc[8];
  #pragma unroll
  for (int d = 0; d < 8; ++d) pacc[d] = 0.f;

  float xc[8], zg[8];                     // per-lane half-channels, live across scan

  const int xbase = (n>>7)*262144 + (n&127)*8 + c;
  float xcur = xg[xbase + t2*1024];       // chunk 0 prefetch

  #pragma unroll 1
  for (int ch = 0; ch < 8; ++ch) {
    // rolling prefetch of next chunk's x (wraps to cached chunk-0 line at ch=7)
    float xnext = xg[xbase + (((ch+1)&7)*32 + t2)*1024];

    if (ch > 0) {
      __syncthreads();                    // post done reading y rows
      if (lane < 48) s_xy[(lane>>4)*17 + (lane&15)] = s_xy[((lane>>4)+32)*17 + (lane&15)];
      __syncthreads();                    // copy done before A1 overwrites tail rows
    }
    // ---- A1: lift + in_proj (lane writes its half's 8 x_in cols; zg in regs) ----
    {
      float z[8];
      #pragma unroll
      for (int d = 0; d < 8; ++d) z[d] = xcur * lwg[c*8+d] + lbg[c*8+d];  // uniform -> s_load
      float* xrow = s_xy + (t2+3)*17 + hb*8;
      #pragma unroll
      for (int j = 0; j < 8; ++j) {
        const float* wr = s_w + IPW + (hb*8+j)*8;
        float4 w0 = *(const float4*)(wr);
        float4 w1 = *(const float4*)(wr+4);
        xrow[j] = z[0]*w0.x + z[1]*w0.y + z[2]*w0.z + z[3]*w0.w
                + z[4]*w1.x + z[5]*w1.y + z[6]*w1.z + z[7]*w1.w;
      }
      #pragma unroll
      for (int j = 0; j < 8; ++j) {
        const float* wr = s_w + IPW + 128 + (hb*8+j)*8;
        float4 w0 = *(const float4*)(wr);
        float4 w1 = *(const float4*)(wr+4);
        zg[j] = z[0]*w0.x + z[1]*w0.y + z[2]*w0.z + z[3]*w0.w
              + z[4]*w1.x + z[5]*w1.y + z[6]*w1.z + z[7]*w1.w;
      }
    }
    __syncthreads();
    // ---- A2: conv + SiLU + x_proj + dt ----
    {
      #pragma unroll
      for (int j = 0; j < 8; ++j) xc[j] = s_w[CB + hb*8 + j];
      #pragma unroll
      for (int k = 0; k < 4; ++k) {
        const float* row = s_xy + (t2+k)*17 + hb*8;
        #pragma unroll
        for (int j = 0; j < 8; ++j) xc[j] += row[j] * s_w[CW + (hb*8+j)*4 + k];
      }
      #pragma unroll
      for (int j = 0; j < 8; ++j) xc[j] = siluf(xc[j]);
      // full 16-wide xc via partner exchange
      float xcf[16];
      #pragma unroll
      for (int j = 0; j < 8; ++j) {
        float p = __shfl_xor(xc[j], 1);
        xcf[j]   = hb ? p : xc[j];
        xcf[8+j] = hb ? xc[j] : p;
      }
      // dtlo = row 0 (both halves compute it; uniform address -> LDS broadcast)
      const float dtlo = dot16(s_w + XPW, xcf);
      // x_proj rows: hb=0 -> rows 1..16 (B), hb=1 -> rows 17..32 (C)
      // groups of 4 -> immediate float4 store (NO intermediate array -> no scratch)
      {
        const float* base = s_w + XPW + 16 + hb*256;
        float* bc = s_BC + t2*36 + hb*16;
        #pragma unroll
        for (int g = 0; g < 4; ++g) {
          float a0 = dot16(base + (g*4+0)*16, xcf);
          float a1 = dot16(base + (g*4+1)*16, xcf);
          float a2 = dot16(base + (g*4+2)*16, xcf);
          float a3 = dot16(base + (g*4+3)*16, xcf);
          *(float4*)(bc + g*4) = make_float4(a0, a1, a2, a3);
        }
      }
      // dt (softplus) + xc, separate odd-stride buffers (conflict-free)
      #pragma unroll
      for (int j = 0; j < 8; ++j) {
        const int i = hb*8 + j;
        s_dt[t2*17 + i] = softplusf(dtlo * s_w[DTW+i] + s_w[DTB+i]);
        s_xc[t2*17 + i] = xc[j];
      }
    }
    __syncthreads();
    // ---- scan: 32 sequential steps, 4 f32 states/lane ----
    {
      const float* pB = s_BC + sg*4;
      const float* pC = s_BC + 16 + sg*4;
      float* py = s_xy + di;
      #pragma unroll 4
      for (int tl = 0; tl < 32; ++tl) {
        float4 bv = *(const float4*)(pB + tl*36);   // broadcast, conflict-free
        float4 cv = *(const float4*)(pC + tl*36);
        float dtv = s_dt[tl*17 + di];
        float xcv = s_xc[tl*17 + di];
        float w  = dtv * xcv;
        float e0 = fexp2(dtv*Am0);
        float e1 = fexp2(dtv*Am1);
        float e2 = fexp2(dtv*Am2);
        float e3 = fexp2(dtv*Am3);
        h0 = h0*e0 + w*bv.x;
        h1 = h1*e1 + w*bv.y;
        h2 = h2*e2 + w*bv.z;
        h3 = h3*e3 + w*bv.w;
        float yp = h0*cv.x + h1*cv.y + h2*cv.z + h3*cv.w;
        yp += __shfl_xor(yp, 1);
        yp += __shfl_xor(yp, 2);
        if (sg == 0) py[tl*17] = yp;     // y overlays dead conv rows 0..31
      }
    }
    __syncthreads();
    // ---- post: gate + out/blk proj + pooled accumulate ----
    {
      const float* yrow = s_xy + t2*17 + hb*8;
      float yf[8];
      #pragma unroll
      for (int j = 0; j < 8; ++j) {
        const int i = hb*8 + j;
        float g = siluf(zg[j]);
        yf[j] = (yrow[j] + s_w[DSK+i]*xc[j]) * g;
      }
      float outv[8];
      #pragma unroll
      for (int d = 0; d < 8; ++d) {
        const float* wr = s_w + OW + d*16 + hb*8;
        float4 w0 = *(const float4*)(wr);
        float4 w1 = *(const float4*)(wr+4);
        float acc = yf[0]*w0.x + yf[1]*w0.y + yf[2]*w0.z + yf[3]*w0.w
                  + yf[4]*w1.x + yf[5]*w1.y + yf[6]*w1.z + yf[7]*w1.w;
        acc += __shfl_xor(acc, 1);       // combine halves -> full dot in both lanes
        outv[d] = acc;
      }
      #pragma unroll
      for (int d = 0; d < 8; ++d) {
        float acc = bbg[c*8+d];          // uniform -> s_load
        #pragma unroll
        for (int d2 = 0; d2 < 8; ++d2) acc += outv[d2] * bwg[c*64 + d*8 + d2];
        pacc[d] += siluf(acc);           // both halves duplicate -> scale 1/512 at end
      }
    }
    xcur = xnext;
  }

  // ---- reduce pooled over 64 lanes (each t counted twice), write feat ----
  #pragma unroll
  for (int d = 0; d < 8; ++d) {
    float v = pacc[d];
    v += __shfl_xor(v, 1);
    v += __shfl_xor(v, 2);
    v += __shfl_xor(v, 4);
    v += __shfl_xor(v, 8);
    v += __shfl_xor(v, 16);
    v += __shfl_xor(v, 32);
    pacc[d] = v;
  }
  if (lane == 0) {
    #pragma unroll
    for (int d = 0; d < 8; ++d) feat[n*64 + c*8 + d] = pacc[d] * (1.0f/512.0f);
  }
}

// LayerNorm over the 64-wide feature dim; one wave per row
__global__ __launch_bounds__(64) void ln_k(const float* __restrict__ feat,
    const float* __restrict__ g, const float* __restrict__ b, float* __restrict__ out)
{
  const int row = blockIdx.x;
  const int l = threadIdx.x;
  float v = feat[row*64 + l];
  float s = v, q = v*v;
  #pragma unroll
  for (int m = 1; m < 64; m <<= 1) { s += __shfl_xor(s, m); q += __shfl_xor(q, m); }
  float mu  = s * (1.0f/64.0f);
  float var = q * (1.0f/64.0f) - mu*mu;
  float rs  = __builtin_amdgcn_rsqf(var + 1e-5f);
  out[row*64 + l] = (v - mu) * rs * g[l] + b[l];
}

extern "C" void kernel_launch(void* const* d_in, const int* in_sizes, int n_in,
                              void* d_out, int out_size, void* d_ws, size_t ws_size,
                              hipStream_t stream)
{
  const float* xg    = (const float*)d_in[0];
  const float* lwg   = (const float*)d_in[1];
  const float* lbg   = (const float*)d_in[2];
  const float* ipwg  = (const float*)d_in[3];
  const float* cwg   = (const float*)d_in[4];
  const float* cbg   = (const float*)d_in[5];
  const float* xpwg  = (const float*)d_in[6];
  const float* dtwg  = (const float*)d_in[7];
  const float* dtbg  = (const float*)d_in[8];
  const float* alogg = (const float*)d_in[9];
  const float* dskg  = (const float*)d_in[10];
  const float* owg   = (const float*)d_in[11];
  const float* bwg   = (const float*)d_in[12];
  const float* bbg   = (const float*)d_in[13];
  const float* lng   = (const float*)d_in[14];
  const float* lnb   = (const float*)d_in[15];
  float* feat = (float*)d_ws;   // 512*64 f32 = 128 KB scratch

  mamba_k<<<dim3(4096), dim3(64), 0, stream>>>(xg, lwg, lbg, ipwg, cwg, cbg, xpwg,
                                               dtwg, dtbg, alogg, dskg, owg, bwg, bbg, feat);
  ln_k<<<dim3(512), dim3(64), 0, stream>>>(feat, lng, lnb, (float*)d_out);
}